// Round 1
// baseline (85.360 us; speedup 1.0000x reference)
//
#include <hip/hip_runtime.h>
#include <math.h>

#define BB 4
#define CC 2
#define HH 2048
#define WW 128
#define HP (HH + 2)   // 2050
#define WP (WW + 2)   // 130
#define PP 128        // pooled size
#define ROWS 8

// ---------------------------------------------------------------------------
// Kernel 1: adaptive avg pool (exact 16x1 block mean) + 1x1 conv + sigmoid
// fm[b][c][i][j], i = pooled row (16 rows each), j = col (1:1)
// ---------------------------------------------------------------------------
__global__ void k_fm(const float* __restrict__ rgb, const float* __restrict__ w_fm,
                     float* __restrict__ fm) {
    int j = threadIdx.x;              // 0..127
    int bi = blockIdx.x;              // b*128 + i
    int b = bi >> 7, i = bi & 127;
    const float* r0 = rgb + ((size_t)(b * 2 + 0) * HH + (size_t)i * 16) * WW + j;
    const float* r1 = rgb + ((size_t)(b * 2 + 1) * HH + (size_t)i * 16) * WW + j;
    float s0 = 0.f, s1 = 0.f;
#pragma unroll
    for (int a = 0; a < 16; ++a) { s0 += r0[a * WW]; s1 += r1[a * WW]; }
    s0 *= (1.f / 16.f); s1 *= (1.f / 16.f);
    float f0 = w_fm[0] * s0 + w_fm[1] * s1;
    float f1 = w_fm[2] * s0 + w_fm[3] * s1;
    fm[((size_t)(b * 2 + 0) * PP + i) * PP + j] = 1.f / (1.f + expf(-f0));
    fm[((size_t)(b * 2 + 1) * PP + i) * PP + j] = 1.f / (1.f + expf(-f1));
}

// ---------------------------------------------------------------------------
// Kernel 2: mat = rgb @ fm + rgb  (per b,c: [2048x128]@[128x128]),
//           fs = w_fs @ mat (1x1 over channels), pack xp = [sar0,sar1,fs0,fs1]
// xp layout: [B][HP][WP][4] float, zero border (from memset)
// ---------------------------------------------------------------------------
__global__ void k_mat(const float* __restrict__ rgb, const float* __restrict__ sar,
                      const float* __restrict__ w_fs, const float* __restrict__ fm,
                      float* __restrict__ xp) {
    __shared__ float rows[2][ROWS][WW];
    int w = threadIdx.x;              // 0..127
    int blk = blockIdx.x;
    int b = blk / (HH / ROWS);
    int h0 = (blk % (HH / ROWS)) * ROWS;

#pragma unroll
    for (int c = 0; c < 2; ++c)
#pragma unroll
        for (int r = 0; r < ROWS; ++r)
            rows[c][r][w] = rgb[((size_t)(b * 2 + c) * HH + (h0 + r)) * WW + w];
    __syncthreads();

    float acc0[ROWS], acc1[ROWS];
#pragma unroll
    for (int r = 0; r < ROWS; ++r) { acc0[r] = rows[0][r][w]; acc1[r] = rows[1][r][w]; }

    const float* fm0 = fm + (size_t)(b * 2 + 0) * PP * PP;
    const float* fm1 = fm + (size_t)(b * 2 + 1) * PP * PP;

    for (int k4 = 0; k4 < PP; k4 += 4) {
        float f0[4], f1[4];
#pragma unroll
        for (int t = 0; t < 4; ++t) {
            f0[t] = fm0[(size_t)(k4 + t) * PP + w];
            f1[t] = fm1[(size_t)(k4 + t) * PP + w];
        }
#pragma unroll
        for (int r = 0; r < ROWS; ++r) {
            float4 a0 = *(const float4*)&rows[0][r][k4];
            float4 a1 = *(const float4*)&rows[1][r][k4];
            acc0[r] += a0.x * f0[0] + a0.y * f0[1] + a0.z * f0[2] + a0.w * f0[3];
            acc1[r] += a1.x * f1[0] + a1.y * f1[1] + a1.z * f1[2] + a1.w * f1[3];
        }
    }

    float wa = w_fs[0], wb = w_fs[1], wc = w_fs[2], wd = w_fs[3];
#pragma unroll
    for (int r = 0; r < ROWS; ++r) {
        float m0 = acc0[r], m1 = acc1[r];
        float fs0 = wa * m0 + wb * m1;
        float fs1 = wc * m0 + wd * m1;
        float s0 = sar[((size_t)(b * 2 + 0) * HH + (h0 + r)) * WW + w];
        float s1 = sar[((size_t)(b * 2 + 1) * HH + (h0 + r)) * WW + w];
        float4 v = make_float4(s0, s1, fs0, fs1);
        *(float4*)(xp + (((size_t)b * HP + (h0 + r + 1)) * WP + (w + 1)) * 4) = v;
    }
}

// ---------------------------------------------------------------------------
// Kernel 3: offset conv (3x3, 18 out ch) fused with deformable sampling + 3x3
// deform conv (O=2). One thread per output pixel.
// ---------------------------------------------------------------------------
__global__ void k_deform(const float* __restrict__ w_p, const float* __restrict__ b_p,
                         const float* __restrict__ w_dc, const float* __restrict__ xp,
                         float* __restrict__ out) {
    __shared__ float swp[648];
    __shared__ float sbp[18];
    __shared__ float swd[72];
    for (int t = threadIdx.x; t < 738; t += 256) {
        if (t < 648) swp[t] = w_p[t];
        else if (t < 666) sbp[t - 648] = b_p[t - 648];
        else swd[t - 666] = w_dc[t - 666];
    }
    __syncthreads();

    int idx = blockIdx.x * 256 + threadIdx.x;     // 0 .. B*H*W-1
    int b = idx >> 18;                             // H*W = 262144 = 2^18
    int rem = idx & (HH * WW - 1);
    int h = rem >> 7;                              // W = 128 = 2^7
    int w = rem & (WW - 1);

    const float4* xpb = (const float4*)xp + (size_t)b * HP * WP;

    // 3x3 neighborhood (all 4 channels per point)
    float4 nb[3][3];
#pragma unroll
    for (int dy = 0; dy < 3; ++dy)
#pragma unroll
        for (int dx = 0; dx < 3; ++dx)
            nb[dy][dx] = xpb[(size_t)(h + dy) * WP + (w + dx)];

    // 18 offset channels: off[r] = b_p[r] + sum_{ci,ky,kx} w_p[r,ci,ky,kx]*x[...]
    float off[18];
#pragma unroll
    for (int r = 0; r < 18; ++r) {
        float s = sbp[r];
        const float* wr = &swp[r * 36];
#pragma unroll
        for (int dy = 0; dy < 3; ++dy)
#pragma unroll
            for (int dx = 0; dx < 3; ++dx) {
                float4 v = nb[dy][dx];
                int base = dy * 3 + dx;
                s += wr[0 * 9 + base] * v.x;
                s += wr[1 * 9 + base] * v.y;
                s += wr[2 * 9 + base] * v.z;
                s += wr[3 * 9 + base] * v.w;
            }
        off[r] = s;
    }

    float acc0 = 0.f, acc1 = 0.f;
#pragma unroll
    for (int n = 0; n < 9; ++n) {
        int pny = n / 3 - 1;
        int pnx = n % 3 - 1;
        float py = (float)(h + 1 + pny) + off[n];
        float px = (float)(w + 1 + pnx) + off[9 + n];
        float fy = floorf(py), fx = floorf(px);
        float y0f = fminf(fmaxf(fy, 0.f), (float)(HP - 1));
        float y1f = fminf(fmaxf(fy + 1.f, 0.f), (float)(HP - 1));
        float x0f = fminf(fmaxf(fx, 0.f), (float)(WP - 1));
        float x1f = fminf(fmaxf(fx + 1.f, 0.f), (float)(WP - 1));
        int y0 = (int)y0f, y1 = (int)y1f, x0 = (int)x0f, x1 = (int)x1f;
        float pyc = fminf(fmaxf(py, 0.f), (float)(HP - 1));
        float pxc = fminf(fmaxf(px, 0.f), (float)(WP - 1));
        float ay = 1.f + y0f - pyc;   // g_lt row factor
        float by = 1.f - y1f + pyc;   // g_rb row factor
        float ax = 1.f + x0f - pxc;
        float bx = 1.f - x1f + pxc;
        float g_lt = ay * ax, g_rb = by * bx, g_lb = ay * bx, g_rt = by * ax;

        float4 v_lt = xpb[(size_t)y0 * WP + x0];
        float4 v_rb = xpb[(size_t)y1 * WP + x1];
        float4 v_lb = xpb[(size_t)y0 * WP + x1];
        float4 v_rt = xpb[(size_t)y1 * WP + x0];

        float vx = g_lt * v_lt.x + g_rb * v_rb.x + g_lb * v_lb.x + g_rt * v_rt.x;
        float vy = g_lt * v_lt.y + g_rb * v_rb.y + g_lb * v_lb.y + g_rt * v_rt.y;
        float vz = g_lt * v_lt.z + g_rb * v_rb.z + g_lb * v_lb.z + g_rt * v_rt.z;
        float vw = g_lt * v_lt.w + g_rb * v_rb.w + g_lb * v_lb.w + g_rt * v_rt.w;

        acc0 += vx * swd[0 * 36 + 0 * 9 + n] + vy * swd[0 * 36 + 1 * 9 + n]
              + vz * swd[0 * 36 + 2 * 9 + n] + vw * swd[0 * 36 + 3 * 9 + n];
        acc1 += vx * swd[1 * 36 + 0 * 9 + n] + vy * swd[1 * 36 + 1 * 9 + n]
              + vz * swd[1 * 36 + 2 * 9 + n] + vw * swd[1 * 36 + 3 * 9 + n];
    }

    out[((size_t)(b * 2 + 0) * HH + h) * WW + w] = acc0;
    out[((size_t)(b * 2 + 1) * HH + h) * WW + w] = acc1;
}

// ---------------------------------------------------------------------------
extern "C" void kernel_launch(void* const* d_in, const int* in_sizes, int n_in,
                              void* d_out, int out_size, void* d_ws, size_t ws_size,
                              hipStream_t stream) {
    const float* rgb  = (const float*)d_in[0];
    const float* sar  = (const float*)d_in[1];
    const float* w_fm = (const float*)d_in[2];
    const float* w_fs = (const float*)d_in[3];
    const float* w_p  = (const float*)d_in[4];
    const float* b_p  = (const float*)d_in[5];
    const float* w_dc = (const float*)d_in[6];
    float* out = (float*)d_out;

    float* ws = (float*)d_ws;
    float* fm = ws;                                    // B*2*128*128 = 131072 floats
    float* xp = ws + 131072;                           // B*HP*WP*4 floats (16B aligned)
    size_t xp_bytes = (size_t)BB * HP * WP * 4 * sizeof(float);

    // zero-pad border (and interior; interior is overwritten by k_mat)
    hipMemsetAsync(xp, 0, xp_bytes, stream);

    k_fm<<<BB * 128, 128, 0, stream>>>(rgb, w_fm, fm);
    k_mat<<<BB * (HH / ROWS), 128, 0, stream>>>(rgb, sar, w_fs, fm, xp);
    k_deform<<<(BB * HH * WW) / 256, 256, 0, stream>>>(w_p, b_p, w_dc, xp, out);
}

// Round 2
// 77.382 us; speedup vs baseline: 1.1031x; 1.1031x over previous
//
#include <hip/hip_runtime.h>
#include <math.h>

#define BB 4
#define CC 2
#define HH 2048
#define WW 128
#define HP (HH + 2)   // 2050
#define WP (WW + 2)   // 130
#define PP 128        // pooled size
#define ROWS 8

// ---------------------------------------------------------------------------
// Kernel 0: zero the pad border of xp ([B][HP][WP][4] float4 cells).
// Interior is fully overwritten by k_mat each call.
// Border cells per b: 2*WP (top+bottom rows) + 2*(HP-2) (left/right cols).
// ---------------------------------------------------------------------------
#define BORDER_PER_B (2 * WP + 2 * (HP - 2))   // 4356
__global__ void k_pad(float4* __restrict__ xp) {
    int i = blockIdx.x * 256 + threadIdx.x;
    if (i >= BB * BORDER_PER_B) return;
    int b = i / BORDER_PER_B;
    int r = i - b * BORDER_PER_B;
    int row, col;
    if (r < WP)               { row = 0;      col = r; }
    else if (r < 2 * WP)      { row = HP - 1; col = r - WP; }
    else {
        int j = r - 2 * WP;
        row = 1 + (j >> 1);
        col = (j & 1) ? (WP - 1) : 0;
    }
    xp[((size_t)b * HP + row) * WP + col] = make_float4(0.f, 0.f, 0.f, 0.f);
}

// ---------------------------------------------------------------------------
// Kernel 1: adaptive avg pool (exact 16x1 block mean) + 1x1 conv + sigmoid
// ---------------------------------------------------------------------------
__global__ void k_fm(const float* __restrict__ rgb, const float* __restrict__ w_fm,
                     float* __restrict__ fm) {
    int j = threadIdx.x;              // 0..127
    int bi = blockIdx.x;              // b*128 + i
    int b = bi >> 7, i = bi & 127;
    const float* r0 = rgb + ((size_t)(b * 2 + 0) * HH + (size_t)i * 16) * WW + j;
    const float* r1 = rgb + ((size_t)(b * 2 + 1) * HH + (size_t)i * 16) * WW + j;
    float s0 = 0.f, s1 = 0.f;
#pragma unroll
    for (int a = 0; a < 16; ++a) { s0 += r0[a * WW]; s1 += r1[a * WW]; }
    s0 *= (1.f / 16.f); s1 *= (1.f / 16.f);
    float f0 = w_fm[0] * s0 + w_fm[1] * s1;
    float f1 = w_fm[2] * s0 + w_fm[3] * s1;
    fm[((size_t)(b * 2 + 0) * PP + i) * PP + j] = 1.f / (1.f + expf(-f0));
    fm[((size_t)(b * 2 + 1) * PP + i) * PP + j] = 1.f / (1.f + expf(-f1));
}

// ---------------------------------------------------------------------------
// Kernel 2: mat = rgb @ fm + rgb (per b,c: [2048x128]@[128x128]),
//           fs = w_fs @ mat, pack xp = [sar0,sar1,fs0,fs1].
// rgb row quads have wave-uniform addresses -> compiler emits s_load
// (SMEM pipe), inner loop is pure v_fmac v,s,v. fm loads stay coalesced.
// ---------------------------------------------------------------------------
__global__ __launch_bounds__(128) void k_mat(
        const float* __restrict__ rgb, const float* __restrict__ sar,
        const float* __restrict__ w_fs, const float* __restrict__ fm,
        float* __restrict__ xp) {
    int w = threadIdx.x;              // 0..127
    int blk = blockIdx.x;
    int b = blk / (HH / ROWS);
    int h0 = (blk % (HH / ROWS)) * ROWS;

    const float* rg0 = rgb + ((size_t)(b * 2 + 0) * HH + h0) * WW;  // uniform base
    const float* rg1 = rgb + ((size_t)(b * 2 + 1) * HH + h0) * WW;
    const float* fm0 = fm + (size_t)(b * 2 + 0) * PP * PP;
    const float* fm1 = fm + (size_t)(b * 2 + 1) * PP * PP;

    float acc0[ROWS], acc1[ROWS];
#pragma unroll
    for (int r = 0; r < ROWS; ++r) {                 // residual term
        acc0[r] = rg0[r * WW + w];
        acc1[r] = rg1[r * WW + w];
    }

    for (int k4 = 0; k4 < PP; k4 += 4) {
        float f0[4], f1[4];
#pragma unroll
        for (int t = 0; t < 4; ++t) {
            f0[t] = fm0[(size_t)(k4 + t) * PP + w];  // coalesced vector load
            f1[t] = fm1[(size_t)(k4 + t) * PP + w];
        }
#pragma unroll
        for (int r = 0; r < ROWS; ++r) {
            float4 a0 = *(const float4*)(rg0 + r * WW + k4);   // uniform -> s_load
            float4 a1 = *(const float4*)(rg1 + r * WW + k4);
            acc0[r] += a0.x * f0[0] + a0.y * f0[1] + a0.z * f0[2] + a0.w * f0[3];
            acc1[r] += a1.x * f1[0] + a1.y * f1[1] + a1.z * f1[2] + a1.w * f1[3];
        }
    }

    float wa = w_fs[0], wb = w_fs[1], wc = w_fs[2], wd = w_fs[3];
#pragma unroll
    for (int r = 0; r < ROWS; ++r) {
        float m0 = acc0[r], m1 = acc1[r];
        float fs0 = wa * m0 + wb * m1;
        float fs1 = wc * m0 + wd * m1;
        float s0 = sar[((size_t)(b * 2 + 0) * HH + (h0 + r)) * WW + w];
        float s1 = sar[((size_t)(b * 2 + 1) * HH + (h0 + r)) * WW + w];
        float4 v = make_float4(s0, s1, fs0, fs1);
        *(float4*)(xp + (((size_t)b * HP + (h0 + r + 1)) * WP + (w + 1)) * 4) = v;
    }
}

// ---------------------------------------------------------------------------
// Kernel 3: offset conv (3x3, 18 ch) + deformable bilinear sampling + 3x3
// deform conv (O=2). TWO vertically-adjacent pixels per thread: weight loads
// (uniform -> s_load) amortized 2x, neighborhood rows shared (4 rows for 2
// pixels instead of 6).
// ---------------------------------------------------------------------------
__global__ __launch_bounds__(256) void k_deform(
        const float* __restrict__ w_p, const float* __restrict__ b_p,
        const float* __restrict__ w_dc, const float* __restrict__ xp,
        float* __restrict__ out) {
    int idx = blockIdx.x * 256 + threadIdx.x;   // 0 .. B*(H/2)*W-1
    int b = idx >> 17;                          // (H/2)*W = 131072 = 2^17
    int rem = idx & ((HH / 2) * WW - 1);
    int h2 = rem >> 7;                          // W = 128 = 2^7
    int w = rem & (WW - 1);
    int h = h2 * 2;                             // pixels (h,w) and (h+1,w)

    const float4* xpb = (const float4*)xp + (size_t)b * HP * WP;

    // 4 xp rows x 3 cols neighborhood (float4 = 4 channels per point)
    float4 nb4[4][3];
#pragma unroll
    for (int dy = 0; dy < 4; ++dy)
#pragma unroll
        for (int dx = 0; dx < 3; ++dx)
            nb4[dy][dx] = xpb[(size_t)(h + dy) * WP + (w + dx)];

    // offsets for both pixels: off[p][r]
    float off[2][18];
#pragma unroll
    for (int r = 0; r < 18; ++r) {
        float bias = b_p[r];                    // uniform
        float s0 = bias, s1 = bias;
        const float* wr = w_p + r * 36;         // [ci][ky][kx]
#pragma unroll
        for (int ky = 0; ky < 3; ++ky)
#pragma unroll
            for (int kx = 0; kx < 3; ++kx) {
                float w0 = wr[0 * 9 + ky * 3 + kx];   // uniform -> s_load
                float w1 = wr[1 * 9 + ky * 3 + kx];
                float w2 = wr[2 * 9 + ky * 3 + kx];
                float w3 = wr[3 * 9 + ky * 3 + kx];
                float4 va = nb4[ky][kx];        // pixel 0
                float4 vb = nb4[ky + 1][kx];    // pixel 1
                s0 += w0 * va.x + w1 * va.y + w2 * va.z + w3 * va.w;
                s1 += w0 * vb.x + w1 * vb.y + w2 * vb.z + w3 * vb.w;
            }
        off[0][r] = s0;
        off[1][r] = s1;
    }

#pragma unroll
    for (int p = 0; p < 2; ++p) {
        int hp_ = h + p;
        float acc0 = 0.f, acc1 = 0.f;
#pragma unroll
        for (int n = 0; n < 9; ++n) {
            int pny = n / 3 - 1;
            int pnx = n % 3 - 1;
            float py = (float)(hp_ + 1 + pny) + off[p][n];
            float px = (float)(w + 1 + pnx) + off[p][9 + n];
            float fy = floorf(py), fx = floorf(px);
            float y0f = fminf(fmaxf(fy, 0.f), (float)(HP - 1));
            float y1f = fminf(fmaxf(fy + 1.f, 0.f), (float)(HP - 1));
            float x0f = fminf(fmaxf(fx, 0.f), (float)(WP - 1));
            float x1f = fminf(fmaxf(fx + 1.f, 0.f), (float)(WP - 1));
            int y0 = (int)y0f, y1 = (int)y1f, x0 = (int)x0f, x1 = (int)x1f;
            float pyc = fminf(fmaxf(py, 0.f), (float)(HP - 1));
            float pxc = fminf(fmaxf(px, 0.f), (float)(WP - 1));
            float ay = 1.f + y0f - pyc;
            float by = 1.f - y1f + pyc;
            float ax = 1.f + x0f - pxc;
            float bx = 1.f - x1f + pxc;
            float g_lt = ay * ax, g_rb = by * bx, g_lb = ay * bx, g_rt = by * ax;

            float4 v_lt = xpb[(size_t)y0 * WP + x0];
            float4 v_rb = xpb[(size_t)y1 * WP + x1];
            float4 v_lb = xpb[(size_t)y0 * WP + x1];
            float4 v_rt = xpb[(size_t)y1 * WP + x0];

            float vx = g_lt * v_lt.x + g_rb * v_rb.x + g_lb * v_lb.x + g_rt * v_rt.x;
            float vy = g_lt * v_lt.y + g_rb * v_rb.y + g_lb * v_lb.y + g_rt * v_rt.y;
            float vz = g_lt * v_lt.z + g_rb * v_rb.z + g_lb * v_lb.z + g_rt * v_rt.z;
            float vw = g_lt * v_lt.w + g_rb * v_rb.w + g_lb * v_lb.w + g_rt * v_rt.w;

            acc0 += vx * w_dc[0 * 36 + 0 * 9 + n] + vy * w_dc[0 * 36 + 1 * 9 + n]
                  + vz * w_dc[0 * 36 + 2 * 9 + n] + vw * w_dc[0 * 36 + 3 * 9 + n];
            acc1 += vx * w_dc[1 * 36 + 0 * 9 + n] + vy * w_dc[1 * 36 + 1 * 9 + n]
                  + vz * w_dc[1 * 36 + 2 * 9 + n] + vw * w_dc[1 * 36 + 3 * 9 + n];
        }
        out[((size_t)(b * 2 + 0) * HH + hp_) * WW + w] = acc0;
        out[((size_t)(b * 2 + 1) * HH + hp_) * WW + w] = acc1;
    }
}

// ---------------------------------------------------------------------------
extern "C" void kernel_launch(void* const* d_in, const int* in_sizes, int n_in,
                              void* d_out, int out_size, void* d_ws, size_t ws_size,
                              hipStream_t stream) {
    const float* rgb  = (const float*)d_in[0];
    const float* sar  = (const float*)d_in[1];
    const float* w_fm = (const float*)d_in[2];
    const float* w_fs = (const float*)d_in[3];
    const float* w_p  = (const float*)d_in[4];
    const float* b_p  = (const float*)d_in[5];
    const float* w_dc = (const float*)d_in[6];
    float* out = (float*)d_out;

    float* ws = (float*)d_ws;
    float* fm = ws;                                    // B*2*128*128 = 131072 floats
    float* xp = ws + 131072;                           // B*HP*WP*4 floats (16B aligned)

    k_pad<<<(BB * BORDER_PER_B + 255) / 256, 256, 0, stream>>>((float4*)xp);
    k_fm<<<BB * 128, 128, 0, stream>>>(rgb, w_fm, fm);
    k_mat<<<BB * (HH / ROWS), 128, 0, stream>>>(rgb, sar, w_fs, fm, xp);
    k_deform<<<(BB * (HH / 2) * WW) / 256, 256, 0, stream>>>(w_p, b_p, w_dc, xp, out);
}